// Round 7
// baseline (369.379 us; speedup 1.0000x reference)
//
#include <hip/hip_runtime.h>
#include <stdint.h>

#define TT 512
#define BB 32
#define EE 512
#define HH 2048

typedef __attribute__((ext_vector_type(8))) short short8;   // 8 x bf16 (4 VGPRs)
typedef __attribute__((ext_vector_type(4))) float f32x4;    // MFMA accumulator

// Exchange row stride in floats: 28 = 112 B = 7 x 16B. Bank-quad start
// (7L mod 8) is bijective per 8-lane group -> conflict-free ds_*_b128.
#define ESTR 28

// Barrier: order LDS ops only (no vmem crosses regions anymore).
#define BAR_LGKM() asm volatile("s_waitcnt lgkmcnt(0)\n\ts_barrier" ::: "memory")

static __device__ __forceinline__ float fast_exp(float x) {
    return __builtin_amdgcn_exp2f(x * 1.44269504f);
}
static __device__ __forceinline__ float fast_rcp(float x) {
    return __builtin_amdgcn_rcpf(x);
}

// Packed fp32->bf16 RNE convert: 1 instr per 2 elements.
static __device__ __forceinline__ unsigned cvtpk_bf16(float lo, float hi) {
    unsigned r;
    asm("v_cvt_pk_bf16_f32 %0, %1, %2" : "=v"(r) : "v"(lo), "v"(hi));
    return r;
}

// ---------------------------------------------------------------------------
// Pre-kernel: convert + TRANSPOSE sent (T,B,E) fp32 -> Xb (B,T,E) bf16, and
// convert W (3H,E) fp32 -> bf16. One wave per 512-elem row, grid-stride.
// (B,T,E) makes each qrnn block's X a contiguous 512 KB slab -> dense L2
// lines for the direct A-frag loads.
// ---------------------------------------------------------------------------
__global__ void convert_inputs(const float* __restrict__ X,
                               const float* __restrict__ W,
                               unsigned short* __restrict__ Xb,
                               unsigned short* __restrict__ Wb) {
    const int xRows = TT * BB;             // 16384
    const int totRows = xRows + 3 * HH;    // + 6144 W rows
    const int lane = threadIdx.x & 63;
    const int nw = (gridDim.x * blockDim.x) >> 6;
    for (int r = (blockIdx.x * blockDim.x + threadIdx.x) >> 6; r < totRows; r += nw) {
        const float* src;
        unsigned short* dst;
        if (r < xRows) {
            int t = r >> 5, b = r & 31;    // input row r = t*B + b
            src = X + (size_t)r * EE;
            dst = Xb + ((size_t)b * TT + t) * EE;   // transpose to (B,T,E)
        } else {
            int wr = r - xRows;
            src = W + (size_t)wr * EE;
            dst = Wb + (size_t)wr * EE;
        }
        float4 v0 = *(const float4*)(src + lane * 8);
        float4 v1 = *(const float4*)(src + lane * 8 + 4);
        union { short8 s; unsigned u[4]; } o;
        o.u[0] = cvtpk_bf16(v0.x, v0.y);
        o.u[1] = cvtpk_bf16(v0.z, v0.w);
        o.u[2] = cvtpk_bf16(v1.x, v1.y);
        o.u[3] = cvtpk_bf16(v1.z, v1.w);
        *(short8*)(dst + lane * 8) = o.s;
    }
}

// ---------------------------------------------------------------------------
// Fused QRNN kernel — R11: direct-from-L2 A-frags (no X LDS), 32-t regions.
//
// R6 accounting: kernel runs at 600 TF effective (=25% MfmaUtil, matches);
// pipes aggregate ~85% busy on non-MFMA work. All prior variants kept the
// per-region geometry fixed (16t, X->LDS->regs, 32 barriers). This round
// changes the geometry:
//  - A-frags are contiguous 16 B per lane -> load DIRECTLY from global
//    ((B,T,E) layout). Removes DMA issue, ds_reads, LDS writes, and the
//    vmcnt drain at the barrier (BAR is lgkmcnt-only now).
//  - 32-t regions: 16 barriers/block instead of 32; 48 MFMAs per wave-region
//    in two 24-MFMA bursts (m-tile A: t=ch*32+c, m-tile B: +16).
//  - Exchange stride 28 floats (conflict-free b128, see ESTR).
//  - Tail stays wave-split (R5): s=0 publishes raw + scans; s=1 acts.
//    s=1 keeps its own prev-chunk partials in regs (24 VGPR) and reads
//    only s=0's raw from LDS. Bias enters via s=0's accumulator init.
//
// Hazards:
//  (1) raw(ch) [s=0 writes region ch] vs s=1 read region ch+1: lgkmcnt(0)
//      + BAR(ch). Slot ch&1 rewritten region ch+2; reads retired BAR(ch+1).
//  (2) act(n) [s=1 writes region n+1 to slot n&1] vs s=0 read region n+2:
//      BAR(n+1). Slot rewritten region n+3; reads retired BAR(n+2).
//  (3) vmem: consumed within the region (compiler waits before MFMA use);
//      nothing crosses a barrier -> lgkm-only barrier is sufficient.
//  (4) Barriers wave-uniform: ch uniform; all conditionals barrier-free.
// ---------------------------------------------------------------------------
__launch_bounds__(256, 2)
__global__ void qrnn_fused(const unsigned short* __restrict__ Xb, // bf16 (B,T,E)
                           const unsigned short* __restrict__ Wb, // bf16 (3H,E)
                           const float* __restrict__ bias,        // (3H)
                           float* __restrict__ out)               // (B,H) fp32
{
    __shared__ float rawx[2][2][64][ESTR];   // 28,672 B (s=0 -> s=1)
    __shared__ float actx[2][2][64][ESTR];   // 28,672 B (s=1 -> s=0)
                                             // total 57,344 B -> 2 blocks/CU

    const int tid  = threadIdx.x;
    const int wv   = tid >> 6;         // wave 0..3
    const int lane = tid & 63;
    const int q    = lane >> 4;        // quad 0..3
    const int c    = lane & 15;        // column within 16x16 tile
    const int hi   = wv >> 1;          // h-tile 0..1
    const int s    = wv & 1;           // k-half 0..1

    // XCD-aware swizzle: 2048 blocks = 8 XCDs x 4 batches x 64 h-groups.
    const int id   = blockIdx.x;       // 0..2047
    const int xcd  = id & 7;
    const int slot = id >> 3;          // 0..255 within this XCD
    const int b    = xcd * 4 + (slot >> 6);   // 4 batches per XCD
    const int hgrp = slot & 63;               // 64 h-groups per batch
    const int h    = hgrp * 32 + hi * 16 + c;

    // ---- preload W fragments (this wave's K half); pin into AGPRs ----
    // B-frag layout for 16x16x32: lane holds n = lane&15 (= h), k = q*8 + j.
    short8 wz[8], wf[8], wo[8];
    {
        const unsigned short* wzr = Wb + (size_t)h * EE            + s * 256;
        const unsigned short* wfr = Wb + (size_t)(HH + h) * EE     + s * 256;
        const unsigned short* wor = Wb + (size_t)(2 * HH + h) * EE + s * 256;
#pragma unroll
        for (int k = 0; k < 8; ++k) {
            int e0 = k * 32 + q * 8;
            wz[k] = *(const short8*)(wzr + e0);
            wf[k] = *(const short8*)(wfr + e0);
            wo[k] = *(const short8*)(wor + e0);
        }
    }
#pragma unroll
    for (int k = 0; k < 8; ++k) {
        asm volatile("" : "+a"(wz[k]), "+a"(wf[k]), "+a"(wo[k]));
    }

    // Bias enters once via s=0's accumulator init.
    const float b0 = (s == 0) ? bias[h]          : 0.0f;
    const float b1 = (s == 0) ? bias[HH + h]     : 0.0f;
    const float b2 = (s == 0) ? bias[2 * HH + h] : 0.0f;

    float carry = 0.0f;    // live in s=0 (scan)
    float vmax  = -1e30f;  // live in s=0

    // Block's X slab: (B,T,E) -> contiguous 512 KB starting at b*T*E.
    const unsigned short* Xp = Xb + (size_t)b * TT * EE;
    const int aoff = s * 256 + q * 8;   // k-half + quad offset within a row

    // 24-MFMA burst for one 16-t m-tile starting at absolute row t0+c.
    auto burst = [&](int t0, f32x4& az, f32x4& af, f32x4& ao) {
        const unsigned short* Ab = Xp + (size_t)(t0 + c) * EE + aoff;
        short8 a[8];
#pragma unroll
        for (int k = 0; k < 8; ++k)
            a[k] = *(const short8*)(Ab + k * 32);
#pragma unroll
        for (int k = 0; k < 8; ++k) {
            az = __builtin_amdgcn_mfma_f32_16x16x32_bf16(a[k], wz[k], az, 0, 0, 0);
            af = __builtin_amdgcn_mfma_f32_16x16x32_bf16(a[k], wf[k], af, 0, 0, 0);
            ao = __builtin_amdgcn_mfma_f32_16x16x32_bf16(a[k], wo[k], ao, 0, 0, 0);
        }
    };

    // 16-t scan step on activation vectors (t = q*4 + r within the tile).
    auto scan16 = [&](f32x4 aav, f32x4 mmv, f32x4 oov) {
        float aa[4], mm[4], oo[4];
#pragma unroll
        for (int r = 0; r < 4; ++r) { aa[r] = aav[r]; mm[r] = mmv[r]; oo[r] = oov[r]; }

        float A = aa[0], M = mm[0];
#pragma unroll
        for (int r = 1; r < 4; ++r) { A = aa[r] + mm[r] * A; M = mm[r] * M; }

        float Ap = __shfl_up(A, 16, 64), Mp = __shfl_up(M, 16, 64);
        if (q >= 1) { A = A + M * Ap; M = M * Mp; }
        Ap = __shfl_up(A, 32, 64); Mp = __shfl_up(M, 32, 64);
        if (q >= 2) { A = A + M * Ap; M = M * Mp; }
        float Ae = __shfl_up(A, 16, 64), Me = __shfl_up(M, 16, 64);
        if (q == 0) { Ae = 0.0f; Me = 1.0f; }
        float cc = Ae + Me * carry;

#pragma unroll
        for (int r = 0; r < 4; ++r) {
            cc = aa[r] + mm[r] * cc;
            vmax = fmaxf(vmax, oo[r] * cc);
        }

        float cend = A + M * carry;
        carry = __shfl(cend, 48 + c, 64);
    };

    // act for one m-tile: summed partials -> aa/mm/oo vectors.
    auto act4 = [&](f32x4 sz, f32x4 sf, f32x4 so, f32x4& aav, f32x4& mmv, f32x4& oov) {
#pragma unroll
        for (int r = 0; r < 4; ++r) {
            float e2 = fast_exp(2.0f * sz[r]);
            float z  = 1.0f - 2.0f * fast_rcp(e2 + 1.0f);  // tanh
            float f  = fast_rcp(1.0f + fast_exp(-sf[r]));  // sigmoid
            float o  = fast_rcp(1.0f + fast_exp(-so[r]));  // sigmoid
            aav[r] = f * z;
            mmv[r] = 1.0f - f;
            oov[r] = o;
        }
    };

    f32x4 ownzA, ownfA, ownoA, ownzB, ownfB, ownoB;   // s=1 rotation state

    for (int ch = 0; ch < 16; ++ch) {
        // ---- two 24-MFMA bursts: m-tile A (t=ch*32..+15), B (+16..+31) ----
        f32x4 azA = {b0, b0, b0, b0}, afA = {b1, b1, b1, b1}, aoA = {b2, b2, b2, b2};
        f32x4 azB = {b0, b0, b0, b0}, afB = {b1, b1, b1, b1}, aoB = {b2, b2, b2, b2};
        burst(ch * 32,      azA, afA, aoA);
        burst(ch * 32 + 16, azB, afB, aoB);

        if (s == 0) {
            // publish raw(ch): [azA azB afA afB aoA aoB] at 16-B slots
            float* w = &rawx[ch & 1][hi][lane][0];
            *(f32x4*)(w)      = azA;  *(f32x4*)(w + 4)  = azB;
            *(f32x4*)(w + 8)  = afA;  *(f32x4*)(w + 12) = afB;
            *(f32x4*)(w + 16) = aoA;  *(f32x4*)(w + 20) = aoB;

            // scan(ch-2) from act published last region (slot (ch-2)&1 = ch&1)
            if (ch > 1) {
                const float* e = &actx[ch & 1][hi][lane][0];
                scan16(*(const f32x4*)(e),     *(const f32x4*)(e + 8),  *(const f32x4*)(e + 16));
                scan16(*(const f32x4*)(e + 4), *(const f32x4*)(e + 12), *(const f32x4*)(e + 20));
            }
        } else {
            // act(ch-1): own rotation + partner raw -> activations, publish
            if (ch > 0) {
                const float* rr = &rawx[(ch - 1) & 1][hi][lane][0];
                f32x4 szA = ownzA + *(const f32x4*)(rr);
                f32x4 szB = ownzB + *(const f32x4*)(rr + 4);
                f32x4 sfA = ownfA + *(const f32x4*)(rr + 8);
                f32x4 sfB = ownfB + *(const f32x4*)(rr + 12);
                f32x4 soA = ownoA + *(const f32x4*)(rr + 16);
                f32x4 soB = ownoB + *(const f32x4*)(rr + 20);
                f32x4 aaA, mmA, ooA, aaB, mmB, ooB;
                act4(szA, sfA, soA, aaA, mmA, ooA);
                act4(szB, sfB, soB, aaB, mmB, ooB);
                float* e = &actx[(ch - 1) & 1][hi][lane][0];
                *(f32x4*)(e)      = aaA;  *(f32x4*)(e + 4)  = aaB;
                *(f32x4*)(e + 8)  = mmA;  *(f32x4*)(e + 12) = mmB;
                *(f32x4*)(e + 16) = ooA;  *(f32x4*)(e + 20) = ooB;
            }
            ownzA = azA; ownfA = afA; ownoA = aoA;
            ownzB = azB; ownfB = afB; ownoB = aoB;
        }

        BAR_LGKM();   // one barrier per region (hazards (1)-(2))
    }

    // ---- epilogue: act(15), barrier, scan(14), scan(15) ----
    if (s == 1) {
        const float* rr = &rawx[15 & 1][hi][lane][0];
        f32x4 szA = ownzA + *(const f32x4*)(rr);
        f32x4 szB = ownzB + *(const f32x4*)(rr + 4);
        f32x4 sfA = ownfA + *(const f32x4*)(rr + 8);
        f32x4 sfB = ownfB + *(const f32x4*)(rr + 12);
        f32x4 soA = ownoA + *(const f32x4*)(rr + 16);
        f32x4 soB = ownoB + *(const f32x4*)(rr + 20);
        f32x4 aaA, mmA, ooA, aaB, mmB, ooB;
        act4(szA, sfA, soA, aaA, mmA, ooA);
        act4(szB, sfB, soB, aaB, mmB, ooB);
        float* e = &actx[15 & 1][hi][lane][0];
        *(f32x4*)(e)      = aaA;  *(f32x4*)(e + 4)  = aaB;
        *(f32x4*)(e + 8)  = mmA;  *(f32x4*)(e + 12) = mmB;
        *(f32x4*)(e + 16) = ooA;  *(f32x4*)(e + 20) = ooB;
    }
    BAR_LGKM();

    if (s == 0) {
        {   // scan(14): slot 14&1 = 0
            const float* e = &actx[0][hi][lane][0];
            scan16(*(const f32x4*)(e),     *(const f32x4*)(e + 8),  *(const f32x4*)(e + 16));
            scan16(*(const f32x4*)(e + 4), *(const f32x4*)(e + 12), *(const f32x4*)(e + 20));
        }
        {   // scan(15): slot 1
            const float* e = &actx[1][hi][lane][0];
            scan16(*(const f32x4*)(e),     *(const f32x4*)(e + 8),  *(const f32x4*)(e + 16));
            scan16(*(const f32x4*)(e + 4), *(const f32x4*)(e + 12), *(const f32x4*)(e + 20));
        }

        vmax = fmaxf(vmax, __shfl_xor(vmax, 16, 64));
        vmax = fmaxf(vmax, __shfl_xor(vmax, 32, 64));
        if (q == 0) out[(size_t)b * HH + h] = vmax;
    }
}

// ---------------------------------------------------------------------------
extern "C" void kernel_launch(void* const* d_in, const int* in_sizes, int n_in,
                              void* d_out, int out_size, void* d_ws, size_t ws_size,
                              hipStream_t stream) {
    const float* sent = (const float*)d_in[0];
    // d_in[1] = lengths (unused by the math)
    const float* W    = (const float*)d_in[2];
    const float* bias = (const float*)d_in[3];
    float* out        = (float*)d_out;

    const int nX = TT * BB * EE;        // 8,388,608
    unsigned short* Xb = (unsigned short*)d_ws;
    unsigned short* Wb = Xb + nX;       // 16 MiB offset, 16B-aligned

    convert_inputs<<<1024, 256, 0, stream>>>(sent, W, Xb, Wb);

    dim3 grid(2048);                    // 1-D: swizzled to (xcd, b, hgrp) in-kernel
    qrnn_fused<<<grid, 256, 0, stream>>>(Xb, Wb, bias, out);
}

// Round 9
// 234.745 us; speedup vs baseline: 1.5735x; 1.5735x over previous
//
#include <hip/hip_runtime.h>
#include <stdint.h>

#define TT 512
#define BB 32
#define EE 512
#define HH 2048

typedef __attribute__((ext_vector_type(8))) short short8;   // 8 x bf16 (4 VGPRs)
typedef __attribute__((ext_vector_type(4))) float f32x4;    // MFMA accumulator

// LDS geometry (in shorts)
#define XROW 528            // 512 data + 16 pad: measured 0 bank conflicts;
                            // 520 gave 8.4M conflicts. Row stride 1056 B.
#define XBUF (16 * XROW)    // one 16-t chunk buffer = 8448 shorts (16.5 KB)

static __device__ __forceinline__ float fast_exp(float x) {
    return __builtin_amdgcn_exp2f(x * 1.44269504f);
}
static __device__ __forceinline__ float fast_rcp(float x) {
    return __builtin_amdgcn_rcpf(x);
}

// Packed fp32->bf16 RNE convert: 1 instr per 2 elements.
static __device__ __forceinline__ unsigned cvtpk_bf16(float lo, float hi) {
    unsigned r;
    asm("v_cvt_pk_bf16_f32 %0, %1, %2" : "=v"(r) : "v"(lo), "v"(hi));
    return r;
}

// Async global->LDS DMA, 16 B/lane (wave-uniform LDS base + lane*16).
static __device__ __forceinline__ void load_lds16(const unsigned short* g, unsigned short* l) {
    __builtin_amdgcn_global_load_lds(
        (const __attribute__((address_space(1))) unsigned int*)(uintptr_t)g,
        (__attribute__((address_space(3))) unsigned int*)(uintptr_t)l,
        16, 0, 0);
}

// ---------------------------------------------------------------------------
// Pre-kernel R12: BW-optimal convert. Block-uniform X/W partition (no
// per-thread branch), 16 elems/thread (4 independent float4 loads -> 4
// cvt_pk pairs -> 2 short8 stores), exact cover, max occupancy.
// Roofline: 46 MB read + 23 MB write ~= 13 us. This is the probe for the
// persistent ~60 us bench-minus-qrnn gap.
// ---------------------------------------------------------------------------
__launch_bounds__(256, 8)
__global__ void convert_inputs(const float* __restrict__ X,
                               const float* __restrict__ W,
                               unsigned short* __restrict__ Xb,
                               unsigned short* __restrict__ Wb) {
    // X: 8,388,608 elems = 2048 blocks * 4096; W: 3,145,728 = 768 blocks.
    const int bid = blockIdx.x;
    const float* src;
    unsigned short* dst;
    size_t base;
    if (bid < 2048) { src = X; dst = Xb; base = (size_t)bid * 4096; }
    else            { src = W; dst = Wb; base = (size_t)(bid - 2048) * 4096; }
    size_t j = base + (size_t)threadIdx.x * 16;

    float4 v0 = *(const float4*)(src + j);
    float4 v1 = *(const float4*)(src + j + 4);
    float4 v2 = *(const float4*)(src + j + 8);
    float4 v3 = *(const float4*)(src + j + 12);
    union { short8 s; unsigned u[4]; } o0, o1;
    o0.u[0] = cvtpk_bf16(v0.x, v0.y);
    o0.u[1] = cvtpk_bf16(v0.z, v0.w);
    o0.u[2] = cvtpk_bf16(v1.x, v1.y);
    o0.u[3] = cvtpk_bf16(v1.z, v1.w);
    o1.u[0] = cvtpk_bf16(v2.x, v2.y);
    o1.u[1] = cvtpk_bf16(v2.z, v2.w);
    o1.u[2] = cvtpk_bf16(v3.x, v3.y);
    o1.u[3] = cvtpk_bf16(v3.z, v3.w);
    *(short8*)(dst + j)     = o0.s;
    *(short8*)(dst + j + 8) = o1.s;
}

// ---------------------------------------------------------------------------
// Fused QRNN kernel — R12: EXACT R1 structure (the 172 us best) + s_setprio
// around the MFMA burst (T5: co-resident blocks' tail waves share SIMDs with
// MFMA-issuing waves -> priority gives the matrix pipe the issue slots).
//
// R1-verified structure: K-split 2-way, 4 waves, W pinned in AGPR, X staged
// by global_load_lds DMA (double-buffered, XROW=528), rotated software
// pipeline (region ch issues MFMA(ch), runs tail(ch-1)), early exch read,
// XCD-aware block swizzle, ONE __syncthreads per chunk.
// Hazards: (1) publish(ch) vs tail-read(ch): barrier(ch). (2) tail-read(ch)
// vs re-publish(ch+2): barrier(ch+1). (3) X buf reread/rewrite: lgkm drained
// at barrier. (4) stage(ch+1) DMA vs consume in ch+1: vmcnt drained at
// barrier(ch).
// ---------------------------------------------------------------------------
__launch_bounds__(256, 2)
__global__ void qrnn_fused(const unsigned short* __restrict__ Xb, // bf16 (T,B,E)
                           const unsigned short* __restrict__ Wb, // bf16 (3H,E)
                           const float* __restrict__ bias,        // (3H)
                           float* __restrict__ out)               // (B,H) fp32
{
    __shared__ unsigned short xlds[2 * XBUF];      // 33,792 B
    __shared__ float exch[2][2][64][12];           // 12,288 B  (total 46,080 B)

    const int tid  = threadIdx.x;
    const int wv   = tid >> 6;         // wave 0..3
    const int lane = tid & 63;
    const int q    = lane >> 4;        // quad 0..3
    const int c    = lane & 15;        // column within 16x16 tile
    const int hi   = wv >> 1;          // h-tile 0..1
    const int s    = wv & 1;           // k-half 0..1

    // XCD-aware swizzle: 2048 blocks = 8 XCDs x 4 batches x 64 h-groups.
    const int id   = blockIdx.x;       // 0..2047
    const int xcd  = id & 7;
    const int slot = id >> 3;          // 0..255 within this XCD
    const int b    = xcd * 4 + (slot >> 6);   // 4 batches per XCD
    const int hgrp = slot & 63;               // 64 h-groups per batch
    const int h    = hgrp * 32 + hi * 16 + c;

    // ---- preload W fragments (this wave's K half); pin into AGPRs ----
    // B-frag layout for 16x16x32: lane holds n = lane&15 (= h), k = q*8 + j.
    short8 wz[8], wf[8], wo[8];
    {
        const unsigned short* wzr = Wb + (size_t)h * EE            + s * 256;
        const unsigned short* wfr = Wb + (size_t)(HH + h) * EE     + s * 256;
        const unsigned short* wor = Wb + (size_t)(2 * HH + h) * EE + s * 256;
#pragma unroll
        for (int k = 0; k < 8; ++k) {
            int e0 = k * 32 + q * 8;
            wz[k] = *(const short8*)(wzr + e0);
            wf[k] = *(const short8*)(wfr + e0);
            wo[k] = *(const short8*)(wor + e0);
        }
    }
#pragma unroll
    for (int k = 0; k < 8; ++k) {
        asm volatile("" : "+a"(wz[k]), "+a"(wf[k]), "+a"(wo[k]));
    }

    const float b0 = (s == 0) ? bias[h]          : 0.0f;
    const float b1 = (s == 0) ? bias[HH + h]     : 0.0f;
    const float b2 = (s == 0) ? bias[2 * HH + h] : 0.0f;

    float carry = 0.0f;
    float vmax  = -1e30f;

    // ---- staging: wave wv owns rows wv*4 .. wv*4+3 of each 16-t chunk ----
    const unsigned short* g0 = Xb + ((size_t)(wv * 4) * BB + b) * EE + lane * 8;
    unsigned short* l0 = &xlds[(wv * 4) * XROW];

    auto stage = [&](int n, int slt) {
        const unsigned short* g = g0 + (size_t)n * (16 * BB * EE);
        unsigned short* l = l0 + slt * XBUF;
#pragma unroll
        for (int i = 0; i < 4; ++i)
            load_lds16(g + (size_t)i * (BB * EE), l + i * XROW);
    };

    // tail for one chunk's fully-summed accumulators (s==0 waves only).
    auto do_tail = [&](f32x4 az, f32x4 af, f32x4 ao) {
        float aa[4], mm[4], oo[4];
#pragma unroll
        for (int r = 0; r < 4; ++r) {
            float e2 = fast_exp(2.0f * az[r]);
            float z  = 1.0f - 2.0f * fast_rcp(e2 + 1.0f);  // tanh
            float f  = fast_rcp(1.0f + fast_exp(-af[r]));  // sigmoid
            float o  = fast_rcp(1.0f + fast_exp(-ao[r]));  // sigmoid
            aa[r] = f * z;
            mm[r] = 1.0f - f;
            oo[r] = o;
        }

        float A = aa[0], M = mm[0];
#pragma unroll
        for (int r = 1; r < 4; ++r) { A = aa[r] + mm[r] * A; M = mm[r] * M; }

        float Ap = __shfl_up(A, 16, 64), Mp = __shfl_up(M, 16, 64);
        if (q >= 1) { A = A + M * Ap; M = M * Mp; }
        Ap = __shfl_up(A, 32, 64); Mp = __shfl_up(M, 32, 64);
        if (q >= 2) { A = A + M * Ap; M = M * Mp; }
        float Ae = __shfl_up(A, 16, 64), Me = __shfl_up(M, 16, 64);
        if (q == 0) { Ae = 0.0f; Me = 1.0f; }
        float cc = Ae + Me * carry;

#pragma unroll
        for (int r = 0; r < 4; ++r) {
            cc = aa[r] + mm[r] * cc;
            vmax = fmaxf(vmax, oo[r] * cc);
        }

        float cend = A + M * carry;
        carry = __shfl(cend, 48 + c, 64);
    };

    stage(0, 0);
    __syncthreads();

    f32x4 prevz, prevf, prevo;   // MFMA results of chunk ch-1 (rotation state)

    for (int ch = 0; ch < 32; ++ch) {
        const int buf = ch & 1;
        if (ch < 31) stage(ch + 1, buf ^ 1);

        // ---- prefetch ALL A-frags for this chunk (8 back-to-back b128) ----
        const unsigned short* Abase = &xlds[buf * XBUF + c * XROW + s * 256 + q * 8];
        short8 a[8];
#pragma unroll
        for (int k = 0; k < 8; ++k)
            a[k] = *(const short8*)(Abase + k * 32);

        // ---- early exchange read for tail(ch-1) ----
        f32x4 pz, pf, po;
        if (s == 0 && ch > 0) {
            const float* e = &exch[(ch - 1) & 1][hi][lane][0];
            pz = *(const f32x4*)(e);
            pf = *(const f32x4*)(e + 4);
            po = *(const f32x4*)(e + 8);
        }

        // ---- MFMA burst: 24 MFMAs, 3 independent chains; setprio(1) so
        //      this wave wins issue slots vs co-resident tail waves (T5) ----
        f32x4 az = {b0, b0, b0, b0};
        f32x4 af = {b1, b1, b1, b1};
        f32x4 ao = {b2, b2, b2, b2};
        __builtin_amdgcn_s_setprio(1);
#pragma unroll
        for (int k = 0; k < 8; ++k) {
            az = __builtin_amdgcn_mfma_f32_16x16x32_bf16(a[k], wz[k], az, 0, 0, 0);
            af = __builtin_amdgcn_mfma_f32_16x16x32_bf16(a[k], wf[k], af, 0, 0, 0);
            ao = __builtin_amdgcn_mfma_f32_16x16x32_bf16(a[k], wo[k], ao, 0, 0, 0);
        }
        __builtin_amdgcn_s_setprio(0);

        // ---- s=1 publishes THIS chunk's partials ----
        if (s == 1) {
            float* e = &exch[ch & 1][hi][lane][0];
            *(f32x4*)(e)     = az;
            *(f32x4*)(e + 4) = af;
            *(f32x4*)(e + 8) = ao;
        }

        // ---- tail(ch-1): pure VALU on prev* + p*; overlaps matrix pipe ----
        if (s == 0 && ch > 0) {
            do_tail(prevz + pz, prevf + pf, prevo + po);
        }

        prevz = az; prevf = af; prevo = ao;

        __syncthreads();   // the ONE barrier per chunk (hazards 1-4)
    }

    // ---- epilogue: tail(31) ----
    if (s == 0) {
        const float* e = &exch[31 & 1][hi][lane][0];
        f32x4 pz = *(const f32x4*)(e);
        f32x4 pf = *(const f32x4*)(e + 4);
        f32x4 po = *(const f32x4*)(e + 8);
        do_tail(prevz + pz, prevf + pf, prevo + po);

        vmax = fmaxf(vmax, __shfl_xor(vmax, 16, 64));
        vmax = fmaxf(vmax, __shfl_xor(vmax, 32, 64));
        if (q == 0) out[(size_t)b * HH + h] = vmax;
    }
}

// ---------------------------------------------------------------------------
extern "C" void kernel_launch(void* const* d_in, const int* in_sizes, int n_in,
                              void* d_out, int out_size, void* d_ws, size_t ws_size,
                              hipStream_t stream) {
    const float* sent = (const float*)d_in[0];
    // d_in[1] = lengths (unused by the math)
    const float* W    = (const float*)d_in[2];
    const float* bias = (const float*)d_in[3];
    float* out        = (float*)d_out;

    const int nX = TT * BB * EE;        // 8,388,608
    unsigned short* Xb = (unsigned short*)d_ws;
    unsigned short* Wb = Xb + nX;       // 16 MiB offset, 16B-aligned

    // X: 2048 blocks, W: 768 blocks (4096 elems each, exact cover)
    convert_inputs<<<2816, 256, 0, stream>>>(sent, W, Xb, Wb);

    dim3 grid(2048);                    // 1-D: swizzled to (xcd, b, hgrp) in-kernel
    qrnn_fused<<<grid, 256, 0, stream>>>(Xb, Wb, bias, out);
}